// Round 2
// baseline (1087.347 us; speedup 1.0000x reference)
//
#include <hip/hip_runtime.h>
#include <math.h>

// Problem constants: B=16, K=6 kernels (+1 text channel), H=W=640
#define BB   16
#define KCH  6
#define CH   7
#define NN   409600
#define N4   102400          // float4 per plane
#define BINS 65536
#define EPSF 1e-6f
#define BPB  100             // blocks per plane (N4 / 1024)

// ---- workspace layout (32-bit word offsets) ----
#define HIST_OFF  0                       // BB*BINS words = 4 MB (reused for both radix passes)
#define SMALL_OFF (BB*BINS)
#define POS_OFF   (SMALL_OFF + 0)
#define NEGT_OFF  (SMALL_OFF + 16)
#define PRE_OFF   (SMALL_OFF + 32)
#define RANK_OFF  (SMALL_OFF + 48)
#define THR_OFF   (SMALL_OFF + 64)
#define UOH_OFF   (SMALL_OFF + 80)
#define TEXT_OFF  (SMALL_OFF + 96)        // BB*3 floats
#define KERN_OFF  (SMALL_OFF + 144)       // BB*KCH*3 floats (plane-major)
#define KMASK_OFF (SMALL_OFF + 432)       // byte array BB*N4 (one 4-bit mask per float4)
#define ZERO_WORDS (SMALL_OFF + 432)      // zeroed each call

__device__ __forceinline__ unsigned sortkey(float f) {
    unsigned u = __float_as_uint(f);
    return (u & 0x80000000u) ? ~u : (u | 0x80000000u);
}
__device__ __forceinline__ float sig(float x) {
    return __builtin_amdgcn_rcpf(1.0f + __expf(-x));
}
__device__ __forceinline__ float wred(float v) {
#pragma unroll
    for (int o = 32; o > 0; o >>= 1) v += __shfl_down(v, o, 64);
    return v;
}
__device__ __forceinline__ unsigned wredu(unsigned v) {
#pragma unroll
    for (int o = 32; o > 0; o >>= 1) v += __shfl_down(v, o, 64);
    return v;
}

// Pass A: counts, 16-bit top histogram, kmask bytes. 1600 blocks, each owns
// 1024 contiguous float4 of one (b) plane.
__global__ __launch_bounds__(256) void k_prep(const float* __restrict__ pred,
                                              const float* __restrict__ gt,
                                              const float* __restrict__ tm,
                                              unsigned* __restrict__ ws,
                                              unsigned char* __restrict__ kmask) {
    const int t  = threadIdx.x;
    const int b  = blockIdx.x / BPB;
    const int ii = (blockIdx.x % BPB) * 1024;
    const float4* pt4 = (const float4*)(pred + ((size_t)b * CH + KCH) * NN);
    const float4* g4  = (const float4*)(gt + (size_t)b * NN);
    const float4* m4  = (const float4*)(tm + (size_t)b * NN);
    unsigned* hist = ws + HIST_OFF + (size_t)b * BINS;

    float4 p[4], g[4], m[4];
#pragma unroll
    for (int j = 0; j < 4; j++) {
        int idx = ii + j * 256 + t;
        p[j] = pt4[idx]; g[j] = g4[idx]; m[j] = m4[idx];
    }
    unsigned lpos = 0, lneg = 0;
#pragma unroll
    for (int j = 0; j < 4; j++) {
        unsigned mb = 0;
#pragma unroll
        for (int s = 0; s < 4; s++) {
            float pf = (&p[j].x)[s], gf = (&g[j].x)[s], mf = (&m[j].x)[s];
            bool neg = (gf <= 0.5f);
            lneg += neg ? 1u : 0u;
            lpos += (gf > 0.5f && mf > 0.5f) ? 1u : 0u;
            if (neg) atomicAdd(&hist[sortkey(pf) >> 16], 1u);
            if (pf > 0.f && mf > 0.5f) mb |= (1u << s);
        }
        kmask[(size_t)b * N4 + ii + j * 256 + t] = (unsigned char)mb;
    }
    lpos = wredu(lpos); lneg = wredu(lneg);
    if ((t & 63) == 0) {
        atomicAdd(&ws[POS_OFF + b], lpos);
        atomicAdd(&ws[NEGT_OFF + b], lneg);
    }
}

// Refine pass: histogram of low 16 bits for keys matching the selected top-16 prefix.
__global__ __launch_bounds__(256) void k_refine(const float* __restrict__ pred,
                                                const float* __restrict__ gt,
                                                unsigned* __restrict__ ws) {
    const int t  = threadIdx.x;
    const int b  = blockIdx.x / BPB;
    const int ii = (blockIdx.x % BPB) * 1024;
    const unsigned prefix = ws[PRE_OFF + b];
    const float4* pt4 = (const float4*)(pred + ((size_t)b * CH + KCH) * NN);
    const float4* g4  = (const float4*)(gt + (size_t)b * NN);
    unsigned* hist = ws + HIST_OFF + (size_t)b * BINS;

    float4 p[4], g[4];
#pragma unroll
    for (int j = 0; j < 4; j++) {
        int idx = ii + j * 256 + t;
        p[j] = pt4[idx]; g[j] = g4[idx];
    }
#pragma unroll
    for (int j = 0; j < 4; j++) {
#pragma unroll
        for (int s = 0; s < 4; s++) {
            float pf = (&p[j].x)[s], gf = (&g[j].x)[s];
            if (gf <= 0.5f) {
                unsigned key = sortkey(pf);
                if ((key >> 16) == prefix) atomicAdd(&hist[key & 0xFFFFu], 1u);
            }
        }
    }
}

// Per-batch scan over 65536 bins (descending) to locate rank r. pass=0: also
// compute neg_num/use_ohem, emit prefix+remaining rank. pass=1: emit threshold.
__global__ __launch_bounds__(256) void k_scan(unsigned* __restrict__ ws, int pass) {
    const int b = blockIdx.x;
    const int t = threadIdx.x;
    __shared__ unsigned seg[256];
    __shared__ unsigned suf[256];
    __shared__ unsigned sbin, srem;
    const unsigned* h = ws + HIST_OFF + (size_t)b * BINS;

    unsigned r;
    if (pass == 0) {
        unsigned pos = ws[POS_OFF + b], ntot = ws[NEGT_OFF + b];
        unsigned negnum = min(3u * pos, ntot);
        if (t == 0) {
            ws[UOH_OFF + b] = (pos > 0u && negnum > 0u) ? 1u : 0u;
            sbin = 0u; srem = 1u;
        }
        r = (negnum > 0u) ? negnum : 1u;
    } else {
        r = ws[RANK_OFF + b];
        if (t == 0) { sbin = 0u; srem = 1u; }
    }
    __syncthreads();

    const unsigned* hc = h + t * 256;
    unsigned s = 0;
    for (int i = 0; i < 256; i++) s += hc[i];
    seg[t] = s;
    __syncthreads();
    if (t == 0) {
        unsigned acc = 0;
        for (int c = 255; c >= 0; c--) { suf[c] = acc; acc += seg[c]; }
    }
    __syncthreads();
    unsigned lo = suf[t];
    if (r > lo && r <= lo + seg[t]) {
        unsigned cum = lo;
        for (int i = 255; i >= 0; i--) {
            unsigned c = hc[i];
            if (cum + c >= r) { sbin = (unsigned)(t * 256 + i); srem = r - cum; break; }
            cum += c;
        }
    }
    __syncthreads();
    if (t == 0) {
        if (pass == 0) {
            ws[PRE_OFF + b] = sbin;
            ws[RANK_OFF + b] = srem;
        } else {
            unsigned key = (ws[PRE_OFF + b] << 16) | sbin;
            unsigned orig = (key & 0x80000000u) ? (key & 0x7FFFFFFFu) : ~key;
            ws[THR_OFF + b] = orig;
        }
    }
}

// Fused dice: blocks [0,1600) = text dice; blocks [1600, 1600+9600) = kernel dice.
__global__ __launch_bounds__(256) void k_dice(const float* __restrict__ pred,
                                              const float* __restrict__ gt,
                                              const float* __restrict__ gtk,
                                              const float* __restrict__ tm,
                                              unsigned* __restrict__ ws,
                                              const unsigned char* __restrict__ kmask) {
    const int t = threadIdx.x;
    float a0 = 0.f, a1 = 0.f, a2 = 0.f;

    if (blockIdx.x < BB * BPB) {
        // ---- text dice ----
        const int b  = blockIdx.x / BPB;
        const int ii = (blockIdx.x % BPB) * 1024;
        const float thr = __uint_as_float(ws[THR_OFF + b]);
        const bool uoh = (ws[UOH_OFF + b] != 0u);
        const float4* pt4 = (const float4*)(pred + ((size_t)b * CH + KCH) * NN);
        const float4* g4  = (const float4*)(gt + (size_t)b * NN);
        const float4* m4  = (const float4*)(tm + (size_t)b * NN);
        float4 p[4], g[4], m[4];
#pragma unroll
        for (int j = 0; j < 4; j++) {
            int idx = ii + j * 256 + t;
            p[j] = pt4[idx]; g[j] = g4[idx]; m[j] = m4[idx];
        }
#pragma unroll
        for (int j = 0; j < 4; j++) {
#pragma unroll
            for (int s = 0; s < 4; s++) {
                float pf = (&p[j].x)[s], gf = (&g[j].x)[s], mf = (&m[j].x)[s];
                float sel = uoh ? ((((pf >= thr) || (gf > 0.5f)) && (mf > 0.5f)) ? 1.f : 0.f)
                                : mf;
                float pp = sig(pf) * sel;
                float gg = gf * sel;
                a0 += pp * gg; a1 += pp * pp; a2 += gg * gg;
            }
        }
        a0 = wred(a0); a1 = wred(a1); a2 = wred(a2);
        float* ts = (float*)(ws + TEXT_OFF);
        if ((t & 63) == 0) {
            atomicAdd(&ts[b * 3 + 0], a0);
            atomicAdd(&ts[b * 3 + 1], a1);
            atomicAdd(&ts[b * 3 + 2], a2);
        }
    } else {
        // ---- kernel dice: plane = b*KCH + k ----
        const int bid   = blockIdx.x - BB * BPB;
        const int plane = bid / BPB;
        const int ii    = (bid % BPB) * 1024;
        const int b = plane / KCH;
        const int k = plane % KCH;
        const float4* pk4 = (const float4*)(pred + ((size_t)b * CH + k) * NN);
        const float4* gk4 = (const float4*)(gtk + (size_t)plane * NN);
        const unsigned char* mp = kmask + (size_t)b * N4 + ii;
        float4 p[4], g[4];
        unsigned char mb[4];
#pragma unroll
        for (int j = 0; j < 4; j++) {
            int idx = ii + j * 256 + t;
            p[j] = pk4[idx]; g[j] = gk4[idx];
            mb[j] = mp[j * 256 + t];
        }
#pragma unroll
        for (int j = 0; j < 4; j++) {
#pragma unroll
            for (int s = 0; s < 4; s++) {
                float sel = (float)((mb[j] >> s) & 1u);
                float pf = (&p[j].x)[s], gf = (&g[j].x)[s];
                float pp = sig(pf) * sel;
                float gg = gf * sel;
                a0 += pp * gg; a1 += pp * pp; a2 += gg * gg;
            }
        }
        a0 = wred(a0); a1 = wred(a1); a2 = wred(a2);
        float* kf = (float*)(ws + KERN_OFF);
        if ((t & 63) == 0) {
            atomicAdd(&kf[plane * 3 + 0], a0);
            atomicAdd(&kf[plane * 3 + 1], a1);
            atomicAdd(&kf[plane * 3 + 2], a2);
        }
    }
}

__global__ void k_final(const unsigned* __restrict__ ws, float* __restrict__ out) {
    if (threadIdx.x != 0 || blockIdx.x != 0) return;
    const float* ts = (const float*)(ws + TEXT_OFF);
    const float* ks = (const float*)(ws + KERN_OFF);
    float lt = 0.f;
    for (int b = 0; b < BB; b++) {
        float a = ts[b * 3 + 0], p2 = ts[b * 3 + 1], g2 = ts[b * 3 + 2];
        lt += 1.0f - 2.0f * a / (p2 + g2 + 2.0f * EPSF);
    }
    lt *= (1.0f / BB);
    float lk = 0.f;
    for (int i = 0; i < KCH * BB; i++) {
        float a = ks[i * 3 + 0], p2 = ks[i * 3 + 1], g2 = ks[i * 3 + 2];
        lk += 1.0f - 2.0f * a / (p2 + g2 + 2.0f * EPSF);
    }
    lk *= (1.0f / (KCH * BB));
    out[0] = 0.7f * lt + 0.3f * lk;
}

extern "C" void kernel_launch(void* const* d_in, const int* in_sizes, int n_in,
                              void* d_out, int out_size, void* d_ws, size_t ws_size,
                              hipStream_t stream) {
    const float* pred = (const float*)d_in[0];
    const float* gt   = (const float*)d_in[1];
    const float* gtk  = (const float*)d_in[2];
    const float* tm   = (const float*)d_in[3];
    float* out = (float*)d_out;
    unsigned* ws = (unsigned*)d_ws;
    unsigned char* kmask = (unsigned char*)(ws + KMASK_OFF);

    // zero hist + small state (kmask is fully overwritten by k_prep)
    hipMemsetAsync(ws, 0, (size_t)ZERO_WORDS * 4, stream);

    k_prep<<<BB * BPB, 256, 0, stream>>>(pred, gt, tm, ws, kmask);
    k_scan<<<BB, 256, 0, stream>>>(ws, 0);
    // re-zero hist region for refine pass
    hipMemsetAsync(ws + HIST_OFF, 0, (size_t)BB * BINS * 4, stream);
    k_refine<<<BB * BPB, 256, 0, stream>>>(pred, gt, ws);
    k_scan<<<BB, 256, 0, stream>>>(ws, 1);

    k_dice<<<BB * BPB + BB * KCH * BPB, 256, 0, stream>>>(pred, gt, gtk, tm, ws, kmask);
    k_final<<<1, 64, 0, stream>>>(ws, out);
}